// Round 13
// baseline (376.430 us; speedup 1.0000x reference)
//
#include <hip/hip_runtime.h>

#define N_NODESC 100000
#define N_EDGESC 1600000
#define E_TOTC   1700000
#define NBK      391   // dst buckets of 256 nodes
#define EPB      4096  // edges per bucket-phase block
#define NBA      416   // ceil(E_TOTC/EPB)
#define GBLK     1563  // gemm blocks total (ceil(100000/64))
#define GA       800   // gemm1 blocks co-launched with k_bucket
#define GB       (GBLK - GA)
#define PLMAX    5120  // place LDS sort capacity (bucket max ~4650)

typedef float f32x4 __attribute__((ext_vector_type(4)));
typedef short s16x8 __attribute__((ext_vector_type(8)));

__device__ inline unsigned bf16rne(float x) {
    unsigned u = __float_as_uint(x);
    return (u + 0x7fffu + ((u >> 16) & 1u)) >> 16;
}

// ==================================================================
// Device bodies
// ==================================================================

// ---- W split: W[128][128] f32 -> bf16 hi/lo tables in MFMA-FRAGMENT
// order: fragment f = (ct*4+kb)*64 + lane  (lane = lk*16+lr) holds the
// 8 shorts for column n=ct*16+lr, k = kb*32+lk*8 .. +7. ----
__device__ __forceinline__ void wsplit_body(const float* __restrict__ W,
                                            unsigned short* __restrict__ wt_hi,
                                            unsigned short* __restrict__ wt_lo,
                                            int bid) {
    int of = bid * 256 + threadIdx.x;      // output short index 0..16383
    if (of >= 128 * 128) return;
    int f  = of >> 3, j = of & 7;
    int ct = f >> 8;
    int kb = (f >> 6) & 3;
    int lk = (f >> 4) & 3;
    int lr = f & 15;
    int n = ct * 16 + lr;
    int k = kb * 32 + lk * 8 + j;
    float v = W[k * 128 + n];
    unsigned h = bf16rne(v);
    float rem = v - __uint_as_float(h << 16);
    unsigned l = bf16rne(rem);
    wt_hi[of] = (unsigned short)h;
    wt_lo[of] = (unsigned short)l;
}

// ---- MFMA GEMM (fp32-accurate 3-term bf16 hi/lo split) + logits.
// TWO-STAGE LDS (32 KB footprint -> 5 blocks/CU, was 64 KB / 2):
//   stage hi table -> ah*bh + al*bh MFMAs -> barrier ->
//   stage lo table (same LDS) -> ah*bl MFMAs.
// Hs epilogue buffer (64x128 f32 = 32 KB, unpadded) overlays the same
// LDS after a barrier. Emits int8 h rows + sp{als,scale} + ald. ----
__device__ __forceinline__ void gemm_body(const float* __restrict__ A,
                                          const unsigned short* __restrict__ wt_hi,
                                          const unsigned short* __restrict__ wt_lo,
                                          const float* __restrict__ a_src,
                                          const float* __restrict__ a_dst,
                                          unsigned* __restrict__ h8,
                                          float* __restrict__ sp,
                                          float* __restrict__ ald, int M,
                                          int gbid, void* smem_raw) {
    unsigned short* lw = (unsigned short*)smem_raw;   // 16384 shorts = 32 KB
    int t = threadIdx.x;
    // ---- stage hi table (coalesced, sequential) ----
    {
        const uint4* gh = (const uint4*)wt_hi;
        uint4* lh = (uint4*)lw;           // 2048 uint4
#pragma unroll
        for (int i = 0; i < 8; ++i) lh[i * 256 + t] = gh[i * 256 + t];
    }
    __syncthreads();

    int mbase = gbid * 64;
    int w  = t >> 6;
    int l  = t & 63;
    int lr = l & 15;    // A row within 16-tile / W col within ct
    int lk = l >> 4;    // k-group 0..3
    int row = mbase + w * 16 + lr;
    if (row >= M) row = 0;   // clamp; stores are guarded

    f32x4 acc[8];
#pragma unroll
    for (int ct = 0; ct < 8; ++ct) acc[ct] = (f32x4){0.f, 0.f, 0.f, 0.f};

    const float* arow = A + (size_t)row * 128;
    // ---- stage 1: ah*bh + al*bh ----
#pragma unroll
    for (int kb = 0; kb < 4; ++kb) {
        int klo = kb * 32 + lk * 8;
        float4 a0 = *(const float4*)(arow + klo);
        float4 a1 = *(const float4*)(arow + klo + 4);
        float av[8] = {a0.x, a0.y, a0.z, a0.w, a1.x, a1.y, a1.z, a1.w};
        s16x8 ah, al;
#pragma unroll
        for (int j = 0; j < 8; ++j) {
            unsigned hu = bf16rne(av[j]);
            ah[j] = (short)hu;
            float rem = av[j] - __uint_as_float(hu << 16);
            al[j] = (short)bf16rne(rem);
        }
#pragma unroll
        for (int ct = 0; ct < 8; ++ct) {
            int fo = ((ct * 4 + kb) * 64 + l) * 8;
            const s16x8 bh = *(const s16x8*)(lw + fo);
            acc[ct] = __builtin_amdgcn_mfma_f32_16x16x32_bf16(ah, bh, acc[ct], 0, 0, 0);
            acc[ct] = __builtin_amdgcn_mfma_f32_16x16x32_bf16(al, bh, acc[ct], 0, 0, 0);
        }
    }
    __syncthreads();   // all waves done reading hi table
    // ---- stage lo table into the same LDS ----
    {
        const uint4* gl = (const uint4*)wt_lo;
        uint4* lh = (uint4*)lw;
#pragma unroll
        for (int i = 0; i < 8; ++i) lh[i * 256 + t] = gl[i * 256 + t];
    }
    __syncthreads();
    // ---- stage 2: ah*bl (A row re-read; L1-hot) ----
#pragma unroll
    for (int kb = 0; kb < 4; ++kb) {
        int klo = kb * 32 + lk * 8;
        float4 a0 = *(const float4*)(arow + klo);
        float4 a1 = *(const float4*)(arow + klo + 4);
        float av[8] = {a0.x, a0.y, a0.z, a0.w, a1.x, a1.y, a1.z, a1.w};
        s16x8 ah;
#pragma unroll
        for (int j = 0; j < 8; ++j) ah[j] = (short)bf16rne(av[j]);
#pragma unroll
        for (int ct = 0; ct < 8; ++ct) {
            int fo = ((ct * 4 + kb) * 64 + l) * 8;
            const s16x8 bl = *(const s16x8*)(lw + fo);
            acc[ct] = __builtin_amdgcn_mfma_f32_16x16x32_bf16(ah, bl, acc[ct], 0, 0, 0);
        }
    }
    __syncthreads();   // all waves done reading lo table before Hs overwrite

    float (*Hs)[128] = (float (*)[128])smem_raw;   // 64 x 128 floats = 32768 B
    // C/D layout: col = lane&15, row = (lane>>4)*4 + reg  (within 16x16 tile)
#pragma unroll
    for (int ct = 0; ct < 8; ++ct)
#pragma unroll
        for (int r = 0; r < 4; ++r)
            Hs[w * 16 + lk * 4 + r][ct * 16 + lr] = acc[ct][r];
    __syncthreads();

    // ---- epilogue: logits + int8 quant (round-7 verified) ----
    int m0 = (t >> 4) * 4;
    int cg = t & 15;          // col-group: cols 8cg..8cg+7
    int head  = cg >> 1;
    int half8 = (cg & 1) * 8;
    const float4* asp = (const float4*)(a_src + head * 16 + half8);
    const float4* adp = (const float4*)(a_dst + head * 16 + half8);
    float4 as0 = asp[0], as1 = asp[1];
    float4 ad0 = adp[0], ad1 = adp[1];
    uint2* hb2 = (uint2*)h8;
#pragma unroll
    for (int i = 0; i < 4; ++i) {
        int m = mbase + m0 + i;
        const float4* hrow = (const float4*)&Hs[m0 + i][cg * 8];
        float4 h0 = hrow[0], h1 = hrow[1];
        float a8[8] = {h0.x, h0.y, h0.z, h0.w, h1.x, h1.y, h1.z, h1.w};
        float ps = a8[0]*as0.x + a8[1]*as0.y + a8[2]*as0.z + a8[3]*as0.w
                 + a8[4]*as1.x + a8[5]*as1.y + a8[6]*as1.z + a8[7]*as1.w;
        float pd = a8[0]*ad0.x + a8[1]*ad0.y + a8[2]*ad0.z + a8[3]*ad0.w
                 + a8[4]*ad1.x + a8[5]*ad1.y + a8[6]*ad1.z + a8[7]*ad1.w;
        ps += __shfl_xor(ps, 1, 64);
        pd += __shfl_xor(pd, 1, 64);
        // per-(node,head) max over the 16 cols (pair of col-groups)
        float m8 = 0.f;
#pragma unroll
        for (int j = 0; j < 8; ++j) m8 = fmaxf(m8, fabsf(a8[j]));
        float m16 = fmaxf(m8, __shfl_xor(m8, 1, 64));
        float inv = m16 > 0.f ? 127.f / m16 : 0.f;
        float sc  = m16 * (1.f / 127.f);
        if (m < M) {
            unsigned u0 = 0, u1 = 0;
#pragma unroll
            for (int j = 0; j < 4; ++j) {
                int q = (int)rintf(a8[j] * inv);
                u0 |= ((unsigned)(q & 255)) << (8 * j);
            }
#pragma unroll
            for (int j = 0; j < 4; ++j) {
                int q = (int)rintf(a8[4 + j] * inv);
                u1 |= ((unsigned)(q & 255)) << (8 * j);
            }
            uint2 hb; hb.x = u0; hb.y = u1;
            hb2[(size_t)m * 16 + cg] = hb;   // bytes [cg*8, cg*8+8) of 128B row
            if ((cg & 1) == 0) {
                sp[(size_t)m * 16 + head]     = ps;   // attention logit (src)
                sp[(size_t)m * 16 + 8 + head] = sc;   // dequant scale
                ald[(size_t)m * 8 + head]     = pd;   // attention logit (dst)
            }
        }
    }
}

// ---- bucket scatter body (CSR phase A): LDS counting-sort by bucket,
// then bucket-grouped (mostly-full-line) global writes. ----
__device__ __forceinline__ void bucket_body(const int* __restrict__ ei,
                                            const int* __restrict__ bucketptr,
                                            const int* __restrict__ bbase,
                                            unsigned* __restrict__ tmp,
                                            void* smem_raw, int bid) {
    // LDS: hist[391] cnt[391] gofs[391] sd[512] sorted[4096] = 23124 B
    int* hist = (int*)smem_raw;
    int* cnt  = hist + NBK;
    int* gofs = cnt + NBK;
    int* sd   = gofs + NBK;
    unsigned* sorted = (unsigned*)(sd + 512);
    int t = threadIdx.x;
    for (int i = t; i < NBK; i += 256) hist[i] = 0;
    __syncthreads();

    int e0 = bid * EPB;
    int ss[16], dd[16];
#pragma unroll
    for (int j = 0; j < 16; ++j) {
        int e = e0 + j * 256 + t;
        if (e < E_TOTC) {
            if (e < N_EDGESC) { ss[j] = ei[e]; dd[j] = ei[N_EDGESC + e]; }
            else { ss[j] = dd[j] = e - N_EDGESC; }
            atomicAdd(&hist[dd[j] >> 8], 1);
        } else {
            dd[j] = -1;
        }
    }
    __syncthreads();
    // inclusive scan of hist over 512 padded slots (2 per thread)
    sd[t]       = (t < NBK) ? hist[t] : 0;
    sd[t + 256] = (t + 256 < NBK) ? hist[t + 256] : 0;
    __syncthreads();
    for (int off = 1; off < 512; off <<= 1) {
        int a0 = (t >= off) ? sd[t - off] : 0;
        int a1 = (t + 256 >= off) ? sd[t + 256 - off] : 0;
        __syncthreads();
        sd[t] += a0; sd[t + 256] += a1;
        __syncthreads();
    }
    // local exclusive base + (global base - local base); cnt = running cursor
    for (int i = t; i < NBK; i += 256) {
        int lb = sd[i] - hist[i];
        gofs[i] = bucketptr[i] + bbase[bid * NBK + i] - lb;
        cnt[i] = lb;
    }
    __syncthreads();
#pragma unroll
    for (int j = 0; j < 16; ++j) {
        if (dd[j] >= 0) {
            int b = dd[j] >> 8;
            int lpos = atomicAdd(&cnt[b], 1);
            sorted[lpos] = (unsigned)ss[j] | ((unsigned)(dd[j] & 255) << 20);
        }
    }
    __syncthreads();
    // writeout: position i -> bucket = first b with sd[b] > i (binary search),
    // dest = gofs[b] + i. Piecewise-contiguous runs -> few lines per wave.
    int nE = min(EPB, E_TOTC - e0);
    for (int i = t; i < nE; i += 256) {
        int lo = 0, hi = NBK - 1;
        while (lo < hi) { int mid = (lo + hi) >> 1; if (sd[mid] > i) hi = mid; else lo = mid + 1; }
        tmp[gofs[lo] + i] = sorted[i];
    }
}

// ---- place body (CSR phase B): LDS counting-sort by node ->
// rowptr + perfectly sequential ssrc writes. ----
__device__ __forceinline__ void place_body(const unsigned* __restrict__ tmp,
                                           const int* __restrict__ bucketptr,
                                           int* __restrict__ rowptr,
                                           int* __restrict__ ssrc,
                                           void* smem_raw, int b) {
    // LDS: cnt256 sd lcur (3072 B) + svals[PLMAX] (20480 B) = 23552 B
    int* cnt256 = (int*)smem_raw;
    int* sd     = cnt256 + 256;
    int* lcur   = cnt256 + 512;
    int* svals  = cnt256 + 768;
    int t = threadIdx.x;
    int rbeg = bucketptr[b];
    int rend = bucketptr[b + 1];
    int sz = rend - rbeg;
    cnt256[t] = 0;
    __syncthreads();
    if (sz <= PLMAX) {
        unsigned pay[20];
#pragma unroll
        for (int k = 0; k < 20; ++k) {
            int i = k * 256 + t;
            if (i < sz) { pay[k] = tmp[rbeg + i]; atomicAdd(&cnt256[pay[k] >> 20], 1); }
        }
        __syncthreads();
        int v = cnt256[t];
        sd[t] = v;
        __syncthreads();
        for (int off = 1; off < 256; off <<= 1) {
            int x = (t >= off) ? sd[t - off] : 0;
            __syncthreads();
            sd[t] += x;
            __syncthreads();
        }
        int lb = sd[t] - v;   // node-local exclusive base within bucket
        int nd = b * 256 + t;
        if (nd < N_NODESC) rowptr[nd] = rbeg + lb;
        lcur[t] = lb;
        __syncthreads();
#pragma unroll
        for (int k = 0; k < 20; ++k) {
            int i = k * 256 + t;
            if (i < sz) {
                int lpos = atomicAdd(&lcur[pay[k] >> 20], 1);
                svals[lpos] = (int)(pay[k] & 0xFFFFFu);
            }
        }
        __syncthreads();
        for (int i = t; i < sz; i += 256) ssrc[rbeg + i] = svals[i];
    } else {
        // fallback: original direct-scatter path (never expected at this size)
        for (int e = rbeg + t; e < rend; e += 256)
            atomicAdd(&cnt256[tmp[e] >> 20], 1);
        __syncthreads();
        int v = cnt256[t];
        sd[t] = v;
        __syncthreads();
        for (int off = 1; off < 256; off <<= 1) {
            int x = (t >= off) ? sd[t - off] : 0;
            __syncthreads();
            sd[t] += x;
            __syncthreads();
        }
        int rp = rbeg + sd[t] - v;
        int nd = b * 256 + t;
        if (nd < N_NODESC) rowptr[nd] = rp;
        lcur[t] = rp;
        __syncthreads();
        for (int e = rbeg + t; e < rend; e += 256) {
            unsigned p = tmp[e];
            int pos = atomicAdd(&lcur[p >> 20], 1);
            ssrc[pos] = p & 0xFFFFFu;
        }
    }
}

// ==================================================================
// Kernels
// ==================================================================

// blocks [0,NBA): per-block histogram over ALL E_TOT edges -> hist_g.
// blocks [NBA,NBA+64): W1 split; [+64,+128): W2 split. No global atomics.
__global__ __launch_bounds__(256) void k_cnt_ws(const int* __restrict__ ei,
                                                int* __restrict__ hist_g,
                                                const float* __restrict__ W1,
                                                unsigned short* wt_hi1, unsigned short* wt_lo1,
                                                const float* __restrict__ W2,
                                                unsigned short* wt_hi2, unsigned short* wt_lo2) {
    __shared__ int hist[NBK];
    int b = blockIdx.x;
    if (b >= NBA) {
        if (b < NBA + 64) wsplit_body(W1, wt_hi1, wt_lo1, b - NBA);
        else              wsplit_body(W2, wt_hi2, wt_lo2, b - NBA - 64);
        return;
    }
    int t = threadIdx.x;
    for (int i = t; i < NBK; i += 256) hist[i] = 0;
    __syncthreads();
    int e0 = b * EPB;
#pragma unroll
    for (int j = 0; j < 16; ++j) {
        int e = e0 + j * 256 + t;
        if (e < E_TOTC) {
            int d = (e < N_EDGESC) ? ei[N_EDGESC + e] : (e - N_EDGESC);
            atomicAdd(&hist[d >> 8], 1);
        }
    }
    __syncthreads();
    for (int i = t; i < NBK; i += 256) hist_g[b * NBK + i] = hist[i];
}

// one block per bucket: exclusive scan over the 416 per-block counts
__global__ __launch_bounds__(512) void k_tot(const int* __restrict__ hist_g,
                                             int* __restrict__ bbase,
                                             int* __restrict__ btot) {
    __shared__ int sd[512];
    int b = blockIdx.x;       // bucket
    int t = threadIdx.x;      // block index
    int v = (t < NBA) ? hist_g[t * NBK + b] : 0;
    sd[t] = v;
    __syncthreads();
    for (int off = 1; off < 512; off <<= 1) {
        int x = (t >= off) ? sd[t - off] : 0;
        __syncthreads();
        sd[t] += x;
        __syncthreads();
    }
    if (t < NBA) bbase[t * NBK + b] = sd[t] - v;  // exclusive
    if (t == 511) btot[b] = sd[511];              // bucket total
}

// exclusive scan of 391 bucket totals -> bucketptr
__global__ void k_bscan(const int* __restrict__ btot, int* bucketptr, int* rowptr) {
    __shared__ int sd[512];
    int t = threadIdx.x;
    int v = (t < NBK) ? btot[t] : 0;
    sd[t] = v;
    __syncthreads();
    for (int off = 1; off < 512; off <<= 1) {
        int x = (t >= off) ? sd[t - off] : 0;
        __syncthreads();
        sd[t] += x;
        __syncthreads();
    }
    if (t <= NBK) bucketptr[t] = sd[t] - v;
    if (t == 0) rowptr[N_NODESC] = E_TOTC;
}

// blocks [0,NBA): bucket scatter; [NBA,NBA+GA): gemm1 rows [0, GA*64)
__global__ __launch_bounds__(256) void k_bucket_gemm(const int* __restrict__ ei,
                                                     const int* __restrict__ bucketptr,
                                                     const int* __restrict__ bbase,
                                                     unsigned* __restrict__ tmp,
                                                     const float* __restrict__ A,
                                                     const unsigned short* __restrict__ wt_hi,
                                                     const unsigned short* __restrict__ wt_lo,
                                                     const float* __restrict__ a_src,
                                                     const float* __restrict__ a_dst,
                                                     unsigned* __restrict__ h8,
                                                     float* __restrict__ sp,
                                                     float* __restrict__ ald, int M) {
    __shared__ __align__(16) char smem[32768];   // union: gemm lw/Hs | bucket (23124)
    int b = blockIdx.x;
    if (b < NBA) bucket_body(ei, bucketptr, bbase, tmp, smem, b);
    else         gemm_body(A, wt_hi, wt_lo, a_src, a_dst, h8, sp, ald, M, b - NBA, smem);
}

// blocks [0,NBK): place; [NBK,NBK+GB): gemm1 rows [GA*64, M)
__global__ __launch_bounds__(256) void k_place_gemm(const unsigned* __restrict__ tmp,
                                                    const int* __restrict__ bucketptr,
                                                    int* __restrict__ rowptr,
                                                    int* __restrict__ ssrc,
                                                    const float* __restrict__ A,
                                                    const unsigned short* __restrict__ wt_hi,
                                                    const unsigned short* __restrict__ wt_lo,
                                                    const float* __restrict__ a_src,
                                                    const float* __restrict__ a_dst,
                                                    unsigned* __restrict__ h8,
                                                    float* __restrict__ sp,
                                                    float* __restrict__ ald, int M) {
    __shared__ __align__(16) char smem[32768];   // union: gemm lw/Hs | place (23552)
    int b = blockIdx.x;
    if (b < NBK) place_body(tmp, bucketptr, rowptr, ssrc, smem, b);
    else         gemm_body(A, wt_hi, wt_lo, a_src, a_dst, h8, sp, ald, M, GA + (b - NBK), smem);
}

// standalone gemm (layer 2)
__global__ __launch_bounds__(256) void k_gemm_mfma(const float* __restrict__ A,
                                                   const unsigned short* __restrict__ wt_hi,
                                                   const unsigned short* __restrict__ wt_lo,
                                                   const float* __restrict__ a_src,
                                                   const float* __restrict__ a_dst,
                                                   unsigned* __restrict__ h8,
                                                   float* __restrict__ sp,
                                                   float* __restrict__ ald, int M) {
    __shared__ __align__(16) char smem[32768];
    gemm_body(A, wt_hi, wt_lo, a_src, a_dst, h8, sp, ald, M, blockIdx.x, smem);
}

// ------------------------------------------------------------------
// Weighted aggregation + softmax (round-7 verified optimum, 75.4 us).
// int8 h rows + {als,scale} in one line; 3 lines & 4 line-requests
// per edge (more requests = more MLP; round-9 merge regressed).
// ------------------------------------------------------------------
__global__ __launch_bounds__(256) void k_agg(const unsigned* __restrict__ h8,
                                             const float* __restrict__ sp,
                                             const float* __restrict__ ald,
                                             const int* __restrict__ rowptr,
                                             const int* __restrict__ ssrc,
                                             const float* __restrict__ bias,
                                             float* __restrict__ out,
                                             int n, int do_relu) {
    int wid  = (blockIdx.x * blockDim.x + threadIdx.x) >> 6;
    int lane = threadIdx.x & 63;
    if (wid >= n) return;
    int start = rowptr[wid];
    int end   = rowptr[wid + 1];
    int slot = lane >> 3;  // edge slot 0..7
    int o    = lane & 7;   // head; cols 16o..16o+15

    float ah = ald[(size_t)wid * 8 + o];

    // one coalesced prefetch of up to 64 src ids (clamped -> always valid)
    int spre;
    { int ee = start + lane; spre = ssrc[ee < end ? ee : start]; }

    float acc[16];
#pragma unroll
    for (int j = 0; j < 16; ++j) acc[j] = 0.f;
    float sw = 0.f;

    const uint4* hq = (const uint4*)h8;   // row = 8 uint4 (128B); head o idx s*8+o
    for (int e0 = start; e0 < end; e0 += 16) {
        int eA = e0 + slot;
        int eB = e0 + 8 + slot;
        bool vA = eA < end;
        bool vB = eB < end;
        int rA = eA - start;
        int rB = eB - start;
        int sA = __shfl(spre, rA & 63, 64);
        int sB = __shfl(spre, rB & 63, 64);
        if (rA >= 64 && vA) sA = ssrc[eA];   // deg>64 fallback (rare)
        if (rB >= 64 && vB) sB = ssrc[eB];
        float xA  = sp[(size_t)sA * 16 + o];
        float scA = sp[(size_t)sA * 16 + 8 + o];
        uint4 qa  = hq[(size_t)sA * 8 + o];
        float xB  = sp[(size_t)sB * 16 + o];
        float scB = sp[(size_t)sB * 16 + 8 + o];
        uint4 qb  = hq[(size_t)sB * 8 + o];

        float lA = xA + ah; lA = lA >= 0.f ? lA : 0.2f * lA;
        float wA = vA ? __expf(lA) : 0.f;
        float lB = xB + ah; lB = lB >= 0.f ? lB : 0.2f * lB;
        float wB = vB ? __expf(lB) : 0.f;
        sw += wA + wB;
        float wsA = wA * scA;
        float wsB = wB * scB;
#define ACC4(u, ws, base_) \
        acc[(base_)+0] += (ws) * (float)(char)((u) & 255u); \
        acc[(base_)+1] += (ws) * (float)(char)(((u) >> 8) & 255u); \
        acc[(base_)+2] += (ws) * (float)(char)(((u) >> 16) & 255u); \
        acc[(base_)+3] += (ws) * (float)((int)(u) >> 24);
        ACC4(qa.x, wsA, 0)  ACC4(qa.y, wsA, 4)  ACC4(qa.z, wsA, 8)  ACC4(qa.w, wsA, 12)
        ACC4(qb.x, wsB, 0)  ACC4(qb.y, wsB, 4)  ACC4(qb.z, wsB, 8)  ACC4(qb.w, wsB, 12)
#undef ACC4
    }
    // reduce across the 8 edge slots (lane bits 3,4,5)
#pragma unroll
    for (int j = 0; j < 16; ++j) {
        acc[j] += __shfl_xor(acc[j], 8, 64);
        acc[j] += __shfl_xor(acc[j], 16, 64);
        acc[j] += __shfl_xor(acc[j], 32, 64);
    }
    sw += __shfl_xor(sw, 8, 64);
    sw += __shfl_xor(sw, 16, 64);
    sw += __shfl_xor(sw, 32, 64);
    if (lane < 8) {
        float ish = 1.0f / (sw + 1e-16f);
        const float4* b4 = (const float4*)bias;
        float4* o4 = (float4*)out;
#pragma unroll
        for (int i = 0; i < 4; ++i) {
            float4 bv = b4[o * 4 + i];
            float4 ov = {acc[i*4+0] * ish + bv.x, acc[i*4+1] * ish + bv.y,
                         acc[i*4+2] * ish + bv.z, acc[i*4+3] * ish + bv.w};
            if (do_relu) {
                ov.x = fmaxf(ov.x, 0.f); ov.y = fmaxf(ov.y, 0.f);
                ov.z = fmaxf(ov.z, 0.f); ov.w = fmaxf(ov.w, 0.f);
            }
            o4[(size_t)wid * 32 + o * 4 + i] = ov;
        }
    }
}

// ------------------------------------------------------------------
// Prediction heads
// ------------------------------------------------------------------
__global__ __launch_bounds__(256) void k_heads(const float* __restrict__ z,
                                               const int* __restrict__ tidx,
                                               const int* __restrict__ cidx,
                                               const float* __restrict__ wy1,
                                               const float* __restrict__ by1,
                                               const float* __restrict__ wy0,
                                               const float* __restrict__ by0,
                                               float* __restrict__ out, int M) {
    int wid  = (blockIdx.x * blockDim.x + threadIdx.x) >> 6;
    int lane = threadIdx.x & 63;
    if (wid >= 2 * M) return;
    int which = (wid >= M) ? 1 : 0;
    int i = wid - which * M;
    int idx = which ? cidx[i] : tidx[i];
    float2 zv = ((const float2*)(z + (size_t)idx * 128))[lane];
    float2 w1 = ((const float2*)wy1)[lane];
    float2 w0 = ((const float2*)wy0)[lane];
    float d1 = zv.x * w1.x + zv.y * w1.y;
    float d0 = zv.x * w0.x + zv.y * w0.y;
#pragma unroll
    for (int off = 32; off > 0; off >>= 1) {
        d1 += __shfl_xor(d1, off, 64);
        d0 += __shfl_xor(d0, off, 64);
    }
    if (lane == 0) {
        float y1v = d1 + by1[0]; y1v = y1v >= 0.f ? y1v : 0.01f * y1v;
        float y0v = d0 + by0[0]; y0v = y0v >= 0.f ? y0v : 0.01f * y0v;
        if (which == 0) { out[i] = y1v; out[M + i] = y0v; }
        else            { out[2 * M + i] = y0v; out[3 * M + i] = y1v; }
    }
}

// ------------------------------------------------------------------
extern "C" void kernel_launch(void* const* d_in, const int* in_sizes, int n_in,
                              void* d_out, int out_size, void* d_ws, size_t ws_size,
                              hipStream_t stream) {
    const float* x   = (const float*)d_in[0];
    const int*   ei  = (const int*)d_in[1];
    const int*   tix = (const int*)d_in[2];
    const int*   cix = (const int*)d_in[3];
    const float* W1  = (const float*)d_in[4];
    const float* as1 = (const float*)d_in[5];
    const float* ad1 = (const float*)d_in[6];
    const float* b1  = (const float*)d_in[7];
    const float* W2  = (const float*)d_in[8];
    const float* as2 = (const float*)d_in[9];
    const float* ad2 = (const float*)d_in[10];
    const float* b2  = (const float*)d_in[11];
    const float* wy1 = (const float*)d_in[12];
    const float* by1 = (const float*)d_in[13];
    const float* wy0 = (const float*)d_in[14];
    const float* by0 = (const float*)d_in[15];
    float* out = (float*)d_out;

    // workspace layout
    float* z_buf     = (float*)d_ws;                  // 12.8M f (xZ1)
    unsigned* h8     = (unsigned*)(z_buf + 12800000); // 3.2M u32 (int8 h, 12.8MB)
    float* sp        = (float*)(h8 + 3200000);        // 1.6M f  ({als, scale})
    float* ald       = sp + 1600000;                  // 800k f
    int* rowptr      = (int*)(ald + 800000);          // 100001
    int* bucketptr   = rowptr + 100001;               // 392
    int* btot        = bucketptr + 392;               // 392
    int* ssrc        = btot + 392;                    // 1.7M
    unsigned* tmp    = (unsigned*)(ssrc + E_TOTC);    // 1.7M
    int* hist_g      = (int*)(tmp + E_TOTC);          // 416*391 = 162656
    int* bbase       = hist_g + NBA * NBK;            // 162656
    unsigned short* wt_hi1 = (unsigned short*)(bbase + NBA * NBK); // 16384
    unsigned short* wt_lo1 = wt_hi1 + 16384;                       // 16384
    unsigned short* wt_hi2 = wt_lo1 + 16384;                       // 16384
    unsigned short* wt_lo2 = wt_hi2 + 16384;                       // 16384

    dim3 B(256);
    // ---- CSR count over ALL edges (atomic-free merge) + W splits ----
    k_cnt_ws<<<NBA + 128, B, 0, stream>>>(ei, hist_g, W1, wt_hi1, wt_lo1,
                                          W2, wt_hi2, wt_lo2);
    k_tot<<<NBK, dim3(512), 0, stream>>>(hist_g, bbase, btot);
    k_bscan<<<1, dim3(512), 0, stream>>>(btot, bucketptr, rowptr);
    // ---- CSR phase A (LDS-sorted writes)  ||  gemm1 first 800 blocks ----
    k_bucket_gemm<<<NBA + GA, B, 0, stream>>>(ei, bucketptr, bbase, tmp, x,
                                              wt_hi1, wt_lo1, as1, ad1,
                                              h8, sp, ald, N_NODESC);
    // ---- CSR phase B (LDS-sorted, sequential ssrc)  ||  gemm1 rest ----
    k_place_gemm<<<NBK + GB, B, 0, stream>>>(tmp, bucketptr, rowptr, ssrc, x,
                                             wt_hi1, wt_lo1, as1, ad1,
                                             h8, sp, ald, N_NODESC);
    // ---- layer 1 aggregation ----
    k_agg<<<(N_NODESC + 3) / 4, B, 0, stream>>>(h8, sp, ald, rowptr, ssrc,
                                                b1, z_buf, N_NODESC, 1);
    // ---- layer 2 ----
    k_gemm_mfma<<<GBLK, B, 0, stream>>>(z_buf, wt_hi2, wt_lo2, as2, ad2,
                                        h8, sp, ald, N_NODESC);
    k_agg<<<(N_NODESC + 3) / 4, B, 0, stream>>>(h8, sp, ald, rowptr, ssrc,
                                                b2, out + 80000, N_NODESC, 0);
    // ---- heads ----
    k_heads<<<(2 * 20000 * 64) / 256, B, 0, stream>>>(out + 80000, tix, cix,
                                                      wy1, by1, wy0, by0, out, 20000);
}

// Round 14
// 362.029 us; speedup vs baseline: 1.0398x; 1.0398x over previous
//
#include <hip/hip_runtime.h>

#define N_NODESC 100000
#define N_EDGESC 1600000
#define E_TOTC   1700000
#define NBK      391   // dst buckets of 256 nodes
#define EPB      4096  // edges per bucket-phase block
#define NBA      416   // ceil(E_TOTC/EPB)
#define GBLK     1563  // gemm blocks total (ceil(100000/64))
#define GA       800   // gemm1 blocks co-launched with k_bucket
#define GB       (GBLK - GA)
#define PLMAX    5120  // place LDS sort capacity (bucket max ~4650)

typedef float f32x4 __attribute__((ext_vector_type(4)));
typedef short s16x8 __attribute__((ext_vector_type(8)));

__device__ inline unsigned bf16rne(float x) {
    unsigned u = __float_as_uint(x);
    return (u + 0x7fffu + ((u >> 16) & 1u)) >> 16;
}

// ==================================================================
// Device bodies
// ==================================================================

// ---- W split: W[128][128] f32 -> bf16 hi/lo tables in MFMA-FRAGMENT
// order: fragment f = (ct*4+kb)*64 + lane  (lane = lk*16+lr) holds the
// 8 shorts for column n=ct*16+lr, k = kb*32+lk*8 .. +7. This makes the
// GEMM's LDS staging a straight coalesced copy and the inner-loop
// ds_read_b128 perfectly sequential (zero bank conflicts). ----
__device__ __forceinline__ void wsplit_body(const float* __restrict__ W,
                                            unsigned short* __restrict__ wt_hi,
                                            unsigned short* __restrict__ wt_lo,
                                            int bid) {
    int of = bid * 256 + threadIdx.x;      // output short index 0..16383
    if (of >= 128 * 128) return;
    int f  = of >> 3, j = of & 7;
    int ct = f >> 8;
    int kb = (f >> 6) & 3;
    int lk = (f >> 4) & 3;
    int lr = f & 15;
    int n = ct * 16 + lr;
    int k = kb * 32 + lk * 8 + j;
    float v = W[k * 128 + n];
    unsigned h = bf16rne(v);
    float rem = v - __uint_as_float(h << 16);
    unsigned l = bf16rne(rem);
    wt_hi[of] = (unsigned short)h;
    wt_lo[of] = (unsigned short)l;
}

// ---- MFMA GEMM (fp32-accurate 3-term bf16 hi/lo split) + logits.
// W tables staged into LDS once per block (fragment order -> coalesced
// copy in, conflict-free ds_read_b128 out). Epilogue Hs overlays the
// W-LDS after a barrier. Emits int8 h rows + sp{als,scale} + ald.
// (Round-12 verified: 64KB single-stage beats 32KB two-stage by 9us.)
__device__ __forceinline__ void gemm_body(const float* __restrict__ A,
                                          const unsigned short* __restrict__ wt_hi,
                                          const unsigned short* __restrict__ wt_lo,
                                          const float* __restrict__ a_src,
                                          const float* __restrict__ a_dst,
                                          unsigned* __restrict__ h8,
                                          float* __restrict__ sp,
                                          float* __restrict__ ald, int M,
                                          int gbid, void* smem_raw) {
    unsigned short* lw = (unsigned short*)smem_raw;   // [16384] hi | [16384] lo
    int t = threadIdx.x;
    // ---- stage both W tables (64 KB) into LDS: coalesced, sequential ----
    {
        const uint4* gh = (const uint4*)wt_hi;
        const uint4* gl = (const uint4*)wt_lo;
        uint4* lh = (uint4*)lw;           // 2048 uint4
        uint4* ll = lh + 2048;
#pragma unroll
        for (int i = 0; i < 8; ++i) lh[i * 256 + t] = gh[i * 256 + t];
#pragma unroll
        for (int i = 0; i < 8; ++i) ll[i * 256 + t] = gl[i * 256 + t];
    }
    __syncthreads();

    int mbase = gbid * 64;
    int w  = t >> 6;
    int l  = t & 63;
    int lr = l & 15;    // A row within 16-tile / W col within ct
    int lk = l >> 4;    // k-group 0..3
    int row = mbase + w * 16 + lr;
    if (row >= M) row = 0;   // clamp; stores are guarded

    f32x4 acc[8];
#pragma unroll
    for (int ct = 0; ct < 8; ++ct) acc[ct] = (f32x4){0.f, 0.f, 0.f, 0.f};

    const float* arow = A + (size_t)row * 128;
#pragma unroll
    for (int kb = 0; kb < 4; ++kb) {
        int klo = kb * 32 + lk * 8;
        float4 a0 = *(const float4*)(arow + klo);
        float4 a1 = *(const float4*)(arow + klo + 4);
        float av[8] = {a0.x, a0.y, a0.z, a0.w, a1.x, a1.y, a1.z, a1.w};
        s16x8 ah, al;
#pragma unroll
        for (int j = 0; j < 8; ++j) {
            unsigned hu = bf16rne(av[j]);
            ah[j] = (short)hu;
            float rem = av[j] - __uint_as_float(hu << 16);
            al[j] = (short)bf16rne(rem);
        }
#pragma unroll
        for (int ct = 0; ct < 8; ++ct) {
            int fo = ((ct * 4 + kb) * 64 + l) * 8;
            const s16x8 bh = *(const s16x8*)(lw + fo);
            const s16x8 bl = *(const s16x8*)(lw + 16384 + fo);
            acc[ct] = __builtin_amdgcn_mfma_f32_16x16x32_bf16(ah, bh, acc[ct], 0, 0, 0);
            acc[ct] = __builtin_amdgcn_mfma_f32_16x16x32_bf16(al, bh, acc[ct], 0, 0, 0);
            acc[ct] = __builtin_amdgcn_mfma_f32_16x16x32_bf16(ah, bl, acc[ct], 0, 0, 0);
        }
    }
    __syncthreads();   // all waves done reading W-LDS before Hs overwrite

    float (*Hs)[132] = (float (*)[132])smem_raw;   // 64 x 132 floats = 33792 B
    // C/D layout: col = lane&15, row = (lane>>4)*4 + reg  (within 16x16 tile)
#pragma unroll
    for (int ct = 0; ct < 8; ++ct)
#pragma unroll
        for (int r = 0; r < 4; ++r)
            Hs[w * 16 + lk * 4 + r][ct * 16 + lr] = acc[ct][r];
    __syncthreads();

    // ---- epilogue: logits + int8 quant (round-7 verified) ----
    int m0 = (t >> 4) * 4;
    int cg = t & 15;          // col-group: cols 8cg..8cg+7
    int head  = cg >> 1;
    int half8 = (cg & 1) * 8;
    const float4* asp = (const float4*)(a_src + head * 16 + half8);
    const float4* adp = (const float4*)(a_dst + head * 16 + half8);
    float4 as0 = asp[0], as1 = asp[1];
    float4 ad0 = adp[0], ad1 = adp[1];
    uint2* hb2 = (uint2*)h8;
#pragma unroll
    for (int i = 0; i < 4; ++i) {
        int m = mbase + m0 + i;
        const float4* hrow = (const float4*)&Hs[m0 + i][cg * 8];
        float4 h0 = hrow[0], h1 = hrow[1];
        float a8[8] = {h0.x, h0.y, h0.z, h0.w, h1.x, h1.y, h1.z, h1.w};
        float ps = a8[0]*as0.x + a8[1]*as0.y + a8[2]*as0.z + a8[3]*as0.w
                 + a8[4]*as1.x + a8[5]*as1.y + a8[6]*as1.z + a8[7]*as1.w;
        float pd = a8[0]*ad0.x + a8[1]*ad0.y + a8[2]*ad0.z + a8[3]*ad0.w
                 + a8[4]*ad1.x + a8[5]*ad1.y + a8[6]*ad1.z + a8[7]*ad1.w;
        ps += __shfl_xor(ps, 1, 64);
        pd += __shfl_xor(pd, 1, 64);
        // per-(node,head) max over the 16 cols (pair of col-groups)
        float m8 = 0.f;
#pragma unroll
        for (int j = 0; j < 8; ++j) m8 = fmaxf(m8, fabsf(a8[j]));
        float m16 = fmaxf(m8, __shfl_xor(m8, 1, 64));
        float inv = m16 > 0.f ? 127.f / m16 : 0.f;
        float sc  = m16 * (1.f / 127.f);
        if (m < M) {
            unsigned u0 = 0, u1 = 0;
#pragma unroll
            for (int j = 0; j < 4; ++j) {
                int q = (int)rintf(a8[j] * inv);
                u0 |= ((unsigned)(q & 255)) << (8 * j);
            }
#pragma unroll
            for (int j = 0; j < 4; ++j) {
                int q = (int)rintf(a8[4 + j] * inv);
                u1 |= ((unsigned)(q & 255)) << (8 * j);
            }
            uint2 hb; hb.x = u0; hb.y = u1;
            hb2[(size_t)m * 16 + cg] = hb;   // bytes [cg*8, cg*8+8) of 128B row
            if ((cg & 1) == 0) {
                sp[(size_t)m * 16 + head]     = ps;   // attention logit (src)
                sp[(size_t)m * 16 + 8 + head] = sc;   // dequant scale
                ald[(size_t)m * 8 + head]     = pd;   // attention logit (dst)
            }
        }
    }
}

// ---- bucket scatter body (CSR phase A): LDS counting-sort by bucket,
// then bucket-grouped (mostly-full-line) global writes. ----
__device__ __forceinline__ void bucket_body(const int* __restrict__ ei,
                                            const int* __restrict__ bucketptr,
                                            const int* __restrict__ bbase,
                                            unsigned* __restrict__ tmp,
                                            void* smem_raw, int bid) {
    // LDS: hist[391] cnt[391] gofs[391] sd[512] sorted[4096] = 23124 B
    int* hist = (int*)smem_raw;
    int* cnt  = hist + NBK;
    int* gofs = cnt + NBK;
    int* sd   = gofs + NBK;
    unsigned* sorted = (unsigned*)(sd + 512);
    int t = threadIdx.x;
    for (int i = t; i < NBK; i += 256) hist[i] = 0;
    __syncthreads();

    int e0 = bid * EPB;
    int ss[16], dd[16];
#pragma unroll
    for (int j = 0; j < 16; ++j) {
        int e = e0 + j * 256 + t;
        if (e < E_TOTC) {
            if (e < N_EDGESC) { ss[j] = ei[e]; dd[j] = ei[N_EDGESC + e]; }
            else { ss[j] = dd[j] = e - N_EDGESC; }
            atomicAdd(&hist[dd[j] >> 8], 1);
        } else {
            dd[j] = -1;
        }
    }
    __syncthreads();
    // inclusive scan of hist over 512 padded slots (2 per thread)
    sd[t]       = (t < NBK) ? hist[t] : 0;
    sd[t + 256] = (t + 256 < NBK) ? hist[t + 256] : 0;
    __syncthreads();
    for (int off = 1; off < 512; off <<= 1) {
        int a0 = (t >= off) ? sd[t - off] : 0;
        int a1 = (t + 256 >= off) ? sd[t + 256 - off] : 0;
        __syncthreads();
        sd[t] += a0; sd[t + 256] += a1;
        __syncthreads();
    }
    // local exclusive base + (global base - local base); cnt = running cursor
    for (int i = t; i < NBK; i += 256) {
        int lb = sd[i] - hist[i];
        gofs[i] = bucketptr[i] + bbase[bid * NBK + i] - lb;
        cnt[i] = lb;
    }
    __syncthreads();
#pragma unroll
    for (int j = 0; j < 16; ++j) {
        if (dd[j] >= 0) {
            int b = dd[j] >> 8;
            int lpos = atomicAdd(&cnt[b], 1);
            sorted[lpos] = (unsigned)ss[j] | ((unsigned)(dd[j] & 255) << 20);
        }
    }
    __syncthreads();
    // writeout: position i -> bucket = first b with sd[b] > i (binary search),
    // dest = gofs[b] + i. Piecewise-contiguous runs -> few lines per wave.
    int nE = min(EPB, E_TOTC - e0);
    for (int i = t; i < nE; i += 256) {
        int lo = 0, hi = NBK - 1;
        while (lo < hi) { int mid = (lo + hi) >> 1; if (sd[mid] > i) hi = mid; else lo = mid + 1; }
        tmp[gofs[lo] + i] = sorted[i];
    }
}

// ---- place body (CSR phase B): LDS counting-sort by node ->
// rowptr + perfectly sequential ssrc writes. ----
__device__ __forceinline__ void place_body(const unsigned* __restrict__ tmp,
                                           const int* __restrict__ bucketptr,
                                           int* __restrict__ rowptr,
                                           int* __restrict__ ssrc,
                                           void* smem_raw, int b) {
    // LDS: cnt256 sd lcur (3072 B) + svals[PLMAX] (20480 B) = 23552 B
    int* cnt256 = (int*)smem_raw;
    int* sd     = cnt256 + 256;
    int* lcur   = cnt256 + 512;
    int* svals  = cnt256 + 768;
    int t = threadIdx.x;
    int rbeg = bucketptr[b];
    int rend = bucketptr[b + 1];
    int sz = rend - rbeg;
    cnt256[t] = 0;
    __syncthreads();
    if (sz <= PLMAX) {
        unsigned pay[20];
#pragma unroll
        for (int k = 0; k < 20; ++k) {
            int i = k * 256 + t;
            if (i < sz) { pay[k] = tmp[rbeg + i]; atomicAdd(&cnt256[pay[k] >> 20], 1); }
        }
        __syncthreads();
        int v = cnt256[t];
        sd[t] = v;
        __syncthreads();
        for (int off = 1; off < 256; off <<= 1) {
            int x = (t >= off) ? sd[t - off] : 0;
            __syncthreads();
            sd[t] += x;
            __syncthreads();
        }
        int lb = sd[t] - v;   // node-local exclusive base within bucket
        int nd = b * 256 + t;
        if (nd < N_NODESC) rowptr[nd] = rbeg + lb;
        lcur[t] = lb;
        __syncthreads();
#pragma unroll
        for (int k = 0; k < 20; ++k) {
            int i = k * 256 + t;
            if (i < sz) {
                int lpos = atomicAdd(&lcur[pay[k] >> 20], 1);
                svals[lpos] = (int)(pay[k] & 0xFFFFFu);
            }
        }
        __syncthreads();
        for (int i = t; i < sz; i += 256) ssrc[rbeg + i] = svals[i];
    } else {
        // fallback: original direct-scatter path (never expected at this size)
        for (int e = rbeg + t; e < rend; e += 256)
            atomicAdd(&cnt256[tmp[e] >> 20], 1);
        __syncthreads();
        int v = cnt256[t];
        sd[t] = v;
        __syncthreads();
        for (int off = 1; off < 256; off <<= 1) {
            int x = (t >= off) ? sd[t - off] : 0;
            __syncthreads();
            sd[t] += x;
            __syncthreads();
        }
        int rp = rbeg + sd[t] - v;
        int nd = b * 256 + t;
        if (nd < N_NODESC) rowptr[nd] = rp;
        lcur[t] = rp;
        __syncthreads();
        for (int e = rbeg + t; e < rend; e += 256) {
            unsigned p = tmp[e];
            int pos = atomicAdd(&lcur[p >> 20], 1);
            ssrc[pos] = p & 0xFFFFFu;
        }
    }
}

// ==================================================================
// Kernels
// ==================================================================

// blocks [0,NBA): per-block histogram over ALL E_TOT edges -> hist_g.
// blocks [NBA,NBA+64): W1 split; [+64,+128): W2 split. No global atomics.
__global__ __launch_bounds__(256) void k_cnt_ws(const int* __restrict__ ei,
                                                int* __restrict__ hist_g,
                                                const float* __restrict__ W1,
                                                unsigned short* wt_hi1, unsigned short* wt_lo1,
                                                const float* __restrict__ W2,
                                                unsigned short* wt_hi2, unsigned short* wt_lo2) {
    __shared__ int hist[NBK];
    int b = blockIdx.x;
    if (b >= NBA) {
        if (b < NBA + 64) wsplit_body(W1, wt_hi1, wt_lo1, b - NBA);
        else              wsplit_body(W2, wt_hi2, wt_lo2, b - NBA - 64);
        return;
    }
    int t = threadIdx.x;
    for (int i = t; i < NBK; i += 256) hist[i] = 0;
    __syncthreads();
    int e0 = b * EPB;
#pragma unroll
    for (int j = 0; j < 16; ++j) {
        int e = e0 + j * 256 + t;
        if (e < E_TOTC) {
            int d = (e < N_EDGESC) ? ei[N_EDGESC + e] : (e - N_EDGESC);
            atomicAdd(&hist[d >> 8], 1);
        }
    }
    __syncthreads();
    for (int i = t; i < NBK; i += 256) hist_g[b * NBK + i] = hist[i];
}

// one block per bucket: exclusive scan over the 416 per-block counts
__global__ __launch_bounds__(512) void k_tot(const int* __restrict__ hist_g,
                                             int* __restrict__ bbase,
                                             int* __restrict__ btot) {
    __shared__ int sd[512];
    int b = blockIdx.x;       // bucket
    int t = threadIdx.x;      // block index
    int v = (t < NBA) ? hist_g[t * NBK + b] : 0;
    sd[t] = v;
    __syncthreads();
    for (int off = 1; off < 512; off <<= 1) {
        int x = (t >= off) ? sd[t - off] : 0;
        __syncthreads();
        sd[t] += x;
        __syncthreads();
    }
    if (t < NBA) bbase[t * NBK + b] = sd[t] - v;  // exclusive
    if (t == 511) btot[b] = sd[511];              // bucket total
}

// exclusive scan of 391 bucket totals -> bucketptr
__global__ void k_bscan(const int* __restrict__ btot, int* bucketptr, int* rowptr) {
    __shared__ int sd[512];
    int t = threadIdx.x;
    int v = (t < NBK) ? btot[t] : 0;
    sd[t] = v;
    __syncthreads();
    for (int off = 1; off < 512; off <<= 1) {
        int x = (t >= off) ? sd[t - off] : 0;
        __syncthreads();
        sd[t] += x;
        __syncthreads();
    }
    if (t <= NBK) bucketptr[t] = sd[t] - v;
    if (t == 0) rowptr[N_NODESC] = E_TOTC;
}

// blocks [0,NBA): bucket scatter; [NBA,NBA+GA): gemm1 rows [0, GA*64)
__global__ __launch_bounds__(256) void k_bucket_gemm(const int* __restrict__ ei,
                                                     const int* __restrict__ bucketptr,
                                                     const int* __restrict__ bbase,
                                                     unsigned* __restrict__ tmp,
                                                     const float* __restrict__ A,
                                                     const unsigned short* __restrict__ wt_hi,
                                                     const unsigned short* __restrict__ wt_lo,
                                                     const float* __restrict__ a_src,
                                                     const float* __restrict__ a_dst,
                                                     unsigned* __restrict__ h8,
                                                     float* __restrict__ sp,
                                                     float* __restrict__ ald, int M) {
    __shared__ __align__(16) char smem[65536];   // union: gemm W-LDS/Hs | bucket (23124)
    int b = blockIdx.x;
    if (b < NBA) bucket_body(ei, bucketptr, bbase, tmp, smem, b);
    else         gemm_body(A, wt_hi, wt_lo, a_src, a_dst, h8, sp, ald, M, b - NBA, smem);
}

// blocks [0,NBK): place; [NBK,NBK+GB): gemm1 rows [GA*64, M)
__global__ __launch_bounds__(256) void k_place_gemm(const unsigned* __restrict__ tmp,
                                                    const int* __restrict__ bucketptr,
                                                    int* __restrict__ rowptr,
                                                    int* __restrict__ ssrc,
                                                    const float* __restrict__ A,
                                                    const unsigned short* __restrict__ wt_hi,
                                                    const unsigned short* __restrict__ wt_lo,
                                                    const float* __restrict__ a_src,
                                                    const float* __restrict__ a_dst,
                                                    unsigned* __restrict__ h8,
                                                    float* __restrict__ sp,
                                                    float* __restrict__ ald, int M) {
    __shared__ __align__(16) char smem[65536];   // union: gemm W-LDS/Hs | place (23552)
    int b = blockIdx.x;
    if (b < NBK) place_body(tmp, bucketptr, rowptr, ssrc, smem, b);
    else         gemm_body(A, wt_hi, wt_lo, a_src, a_dst, h8, sp, ald, M, GA + (b - NBK), smem);
}

// standalone gemm (layer 2)
__global__ __launch_bounds__(256) void k_gemm_mfma(const float* __restrict__ A,
                                                   const unsigned short* __restrict__ wt_hi,
                                                   const unsigned short* __restrict__ wt_lo,
                                                   const float* __restrict__ a_src,
                                                   const float* __restrict__ a_dst,
                                                   unsigned* __restrict__ h8,
                                                   float* __restrict__ sp,
                                                   float* __restrict__ ald, int M) {
    __shared__ __align__(16) char smem[65536];
    gemm_body(A, wt_hi, wt_lo, a_src, a_dst, h8, sp, ald, M, blockIdx.x, smem);
}

// ------------------------------------------------------------------
// Weighted aggregation + softmax (round-7 verified optimum, 75.4 us).
// int8 h rows + {als,scale} in one line; 3 lines & 4 line-requests
// per edge (more requests = more MLP; round-9 merge regressed).
// ------------------------------------------------------------------
__global__ __launch_bounds__(256) void k_agg(const unsigned* __restrict__ h8,
                                             const float* __restrict__ sp,
                                             const float* __restrict__ ald,
                                             const int* __restrict__ rowptr,
                                             const int* __restrict__ ssrc,
                                             const float* __restrict__ bias,
                                             float* __restrict__ out,
                                             int n, int do_relu) {
    int wid  = (blockIdx.x * blockDim.x + threadIdx.x) >> 6;
    int lane = threadIdx.x & 63;
    if (wid >= n) return;
    int start = rowptr[wid];
    int end   = rowptr[wid + 1];
    int slot = lane >> 3;  // edge slot 0..7
    int o    = lane & 7;   // head; cols 16o..16o+15

    float ah = ald[(size_t)wid * 8 + o];

    // one coalesced prefetch of up to 64 src ids (clamped -> always valid)
    int spre;
    { int ee = start + lane; spre = ssrc[ee < end ? ee : start]; }

    float acc[16];
#pragma unroll
    for (int j = 0; j < 16; ++j) acc[j] = 0.f;
    float sw = 0.f;

    const uint4* hq = (const uint4*)h8;   // row = 8 uint4 (128B); head o idx s*8+o
    for (int e0 = start; e0 < end; e0 += 16) {
        int eA = e0 + slot;
        int eB = e0 + 8 + slot;
        bool vA = eA < end;
        bool vB = eB < end;
        int rA = eA - start;
        int rB = eB - start;
        int sA = __shfl(spre, rA & 63, 64);
        int sB = __shfl(spre, rB & 63, 64);
        if (rA >= 64 && vA) sA = ssrc[eA];   // deg>64 fallback (rare)
        if (rB >= 64 && vB) sB = ssrc[eB];
        float xA  = sp[(size_t)sA * 16 + o];
        float scA = sp[(size_t)sA * 16 + 8 + o];
        uint4 qa  = hq[(size_t)sA * 8 + o];
        float xB  = sp[(size_t)sB * 16 + o];
        float scB = sp[(size_t)sB * 16 + 8 + o];
        uint4 qb  = hq[(size_t)sB * 8 + o];

        float lA = xA + ah; lA = lA >= 0.f ? lA : 0.2f * lA;
        float wA = vA ? __expf(lA) : 0.f;
        float lB = xB + ah; lB = lB >= 0.f ? lB : 0.2f * lB;
        float wB = vB ? __expf(lB) : 0.f;
        sw += wA + wB;
        float wsA = wA * scA;
        float wsB = wB * scB;
#define ACC4(u, ws, base_) \
        acc[(base_)+0] += (ws) * (float)(char)((u) & 255u); \
        acc[(base_)+1] += (ws) * (float)(char)(((u) >> 8) & 255u); \
        acc[(base_)+2] += (ws) * (float)(char)(((u) >> 16) & 255u); \
        acc[(base_)+3] += (ws) * (float)((int)(u) >> 24);
        ACC4(qa.x, wsA, 0)  ACC4(qa.y, wsA, 4)  ACC4(qa.z, wsA, 8)  ACC4(qa.w, wsA, 12)
        ACC4(qb.x, wsB, 0)  ACC4(qb.y, wsB, 4)  ACC4(qb.z, wsB, 8)  ACC4(qb.w, wsB, 12)
#undef ACC4
    }
    // reduce across the 8 edge slots (lane bits 3,4,5)
#pragma unroll
    for (int j = 0; j < 16; ++j) {
        acc[j] += __shfl_xor(acc[j], 8, 64);
        acc[j] += __shfl_xor(acc[j], 16, 64);
        acc[j] += __shfl_xor(acc[j], 32, 64);
    }
    sw += __shfl_xor(sw, 8, 64);
    sw += __shfl_xor(sw, 16, 64);
    sw += __shfl_xor(sw, 32, 64);
    if (lane < 8) {
        float ish = 1.0f / (sw + 1e-16f);
        const float4* b4 = (const float4*)bias;
        float4* o4 = (float4*)out;
#pragma unroll
        for (int i = 0; i < 4; ++i) {
            float4 bv = b4[o * 4 + i];
            float4 ov = {acc[i*4+0] * ish + bv.x, acc[i*4+1] * ish + bv.y,
                         acc[i*4+2] * ish + bv.z, acc[i*4+3] * ish + bv.w};
            if (do_relu) {
                ov.x = fmaxf(ov.x, 0.f); ov.y = fmaxf(ov.y, 0.f);
                ov.z = fmaxf(ov.z, 0.f); ov.w = fmaxf(ov.w, 0.f);
            }
            o4[(size_t)wid * 32 + o * 4 + i] = ov;
        }
    }
}

// ------------------------------------------------------------------
// Prediction heads
// ------------------------------------------------------------------
__global__ __launch_bounds__(256) void k_heads(const float* __restrict__ z,
                                               const int* __restrict__ tidx,
                                               const int* __restrict__ cidx,
                                               const float* __restrict__ wy1,
                                               const float* __restrict__ by1,
                                               const float* __restrict__ wy0,
                                               const float* __restrict__ by0,
                                               float* __restrict__ out, int M) {
    int wid  = (blockIdx.x * blockDim.x + threadIdx.x) >> 6;
    int lane = threadIdx.x & 63;
    if (wid >= 2 * M) return;
    int which = (wid >= M) ? 1 : 0;
    int i = wid - which * M;
    int idx = which ? cidx[i] : tidx[i];
    float2 zv = ((const float2*)(z + (size_t)idx * 128))[lane];
    float2 w1 = ((const float2*)wy1)[lane];
    float2 w0 = ((const float2*)wy0)[lane];
    float d1 = zv.x * w1.x + zv.y * w1.y;
    float d0 = zv.x * w0.x + zv.y * w0.y;
#pragma unroll
    for (int off = 32; off > 0; off >>= 1) {
        d1 += __shfl_xor(d1, off, 64);
        d0 += __shfl_xor(d0, off, 64);
    }
    if (lane == 0) {
        float y1v = d1 + by1[0]; y1v = y1v >= 0.f ? y1v : 0.01f * y1v;
        float y0v = d0 + by0[0]; y0v = y0v >= 0.f ? y0v : 0.01f * y0v;
        if (which == 0) { out[i] = y1v; out[M + i] = y0v; }
        else            { out[2 * M + i] = y0v; out[3 * M + i] = y1v; }
    }
}

// ------------------------------------------------------------------
extern "C" void kernel_launch(void* const* d_in, const int* in_sizes, int n_in,
                              void* d_out, int out_size, void* d_ws, size_t ws_size,
                              hipStream_t stream) {
    const float* x   = (const float*)d_in[0];
    const int*   ei  = (const int*)d_in[1];
    const int*   tix = (const int*)d_in[2];
    const int*   cix = (const int*)d_in[3];
    const float* W1  = (const float*)d_in[4];
    const float* as1 = (const float*)d_in[5];
    const float* ad1 = (const float*)d_in[6];
    const float* b1  = (const float*)d_in[7];
    const float* W2  = (const float*)d_in[8];
    const float* as2 = (const float*)d_in[9];
    const float* ad2 = (const float*)d_in[10];
    const float* b2  = (const float*)d_in[11];
    const float* wy1 = (const float*)d_in[12];
    const float* by1 = (const float*)d_in[13];
    const float* wy0 = (const float*)d_in[14];
    const float* by0 = (const float*)d_in[15];
    float* out = (float*)d_out;

    // workspace layout
    float* z_buf     = (float*)d_ws;                  // 12.8M f (xZ1)
    unsigned* h8     = (unsigned*)(z_buf + 12800000); // 3.2M u32 (int8 h, 12.8MB)
    float* sp        = (float*)(h8 + 3200000);        // 1.6M f  ({als, scale})
    float* ald       = sp + 1600000;                  // 800k f
    int* rowptr      = (int*)(ald + 800000);          // 100001
    int* bucketptr   = rowptr + 100001;               // 392
    int* btot        = bucketptr + 392;               // 392
    int* ssrc        = btot + 392;                    // 1.7M
    unsigned* tmp    = (unsigned*)(ssrc + E_TOTC);    // 1.7M
    int* hist_g      = (int*)(tmp + E_TOTC);          // 416*391 = 162656
    int* bbase       = hist_g + NBA * NBK;            // 162656
    unsigned short* wt_hi1 = (unsigned short*)(bbase + NBA * NBK); // 16384
    unsigned short* wt_lo1 = wt_hi1 + 16384;                       // 16384
    unsigned short* wt_hi2 = wt_lo1 + 16384;                       // 16384
    unsigned short* wt_lo2 = wt_hi2 + 16384;                       // 16384

    dim3 B(256);
    // ---- CSR count over ALL edges (atomic-free merge) + W splits ----
    k_cnt_ws<<<NBA + 128, B, 0, stream>>>(ei, hist_g, W1, wt_hi1, wt_lo1,
                                          W2, wt_hi2, wt_lo2);
    k_tot<<<NBK, dim3(512), 0, stream>>>(hist_g, bbase, btot);
    k_bscan<<<1, dim3(512), 0, stream>>>(btot, bucketptr, rowptr);
    // ---- CSR phase A (LDS-sorted writes)  ||  gemm1 first 800 blocks ----
    k_bucket_gemm<<<NBA + GA, B, 0, stream>>>(ei, bucketptr, bbase, tmp, x,
                                              wt_hi1, wt_lo1, as1, ad1,
                                              h8, sp, ald, N_NODESC);
    // ---- CSR phase B (LDS-sorted, sequential ssrc)  ||  gemm1 rest ----
    k_place_gemm<<<NBK + GB, B, 0, stream>>>(tmp, bucketptr, rowptr, ssrc, x,
                                             wt_hi1, wt_lo1, as1, ad1,
                                             h8, sp, ald, N_NODESC);
    // ---- layer 1 aggregation ----
    k_agg<<<(N_NODESC + 3) / 4, B, 0, stream>>>(h8, sp, ald, rowptr, ssrc,
                                                b1, z_buf, N_NODESC, 1);
    // ---- layer 2 ----
    k_gemm_mfma<<<GBLK, B, 0, stream>>>(z_buf, wt_hi2, wt_lo2, as2, ad2,
                                        h8, sp, ald, N_NODESC);
    k_agg<<<(N_NODESC + 3) / 4, B, 0, stream>>>(h8, sp, ald, rowptr, ssrc,
                                                b2, out + 80000, N_NODESC, 0);
    // ---- heads ----
    k_heads<<<(2 * 20000 * 64) / 256, B, 0, stream>>>(out + 80000, tix, cix,
                                                      wy1, by1, wy0, by0, out, 20000);
}